// Round 7
// baseline (150.536 us; speedup 1.0000x reference)
//
#include <hip/hip_runtime.h>

// ---------------------------------------------------------------------------
// Output depends ONLY on positions[0:64]. ~14M MACs total.
//
// R15: 2 dispatches (16B counter-memset + ONE 240-block mega-kernel with 4
// producer/consumer levels). Evidence: boundaries cost ~1-1.5us each (R12->
// R14); R11's spin regression was the barrier-forced 128KB staging drain on
// the RELEASE path, not the spin itself; R14's last-arriver (acquire atomic
// -> cross-XCD read) scored absmax 0.0. Here waiters only gate THEMSELVES:
//  blk 0..63   gf    : verbatim K1a (backbone + 32-col gf slice) -> gf_ws,
//                      then fence+release cnt[0].
//  blk 64..191 tpart : verbatim K1b; Wn1 16-col slice staged AT ENTRY
//                      (overlaps gf compute); poll cnt[0]==64; stage gf_s;
//                      -> tpart_ws; release cnt[1].
//  blk 192..223 agg  : verbatim K2; Wn2 8-col slice staged AT ENTRY; poll
//                      cnt[1]==128; stage tp_s; tbar+agg -> agg_ws;
//                      release cnt[2].
//  blk 224..239 heads: verbatim K34; Wh1 32-col slice staged AT ENTRY; poll
//                      cnt[2]==32; h1h -> h1h_ws; last-arriver (cnt[3])
//                      computes the 4 strictly-sequential dots -> out.
// 240 blocks x ~100KB LDS = 1 blk/CU <= 256 CUs: co-resident by capacity.
// All polls guard-bounded (worst case absmax fail, never a hang).
//
// BIT-EXACTNESS: harness demands bit-exact (R1 failed by one ulp). Every
// per-output accumulation keeps the VERBATIM expression structure and
// ascending chunk order from rounds that scored absmax 0.0. Only the sync
// mechanism changed (kernel boundaries -> acquire/release counters, the
// R14-proven pattern). f32 global round-trips are lossless. Do not
// reassociate; do not regroup.
// ---------------------------------------------------------------------------

__device__ __forceinline__ void async_cp16(const float* g, float* l) {
    __builtin_amdgcn_global_load_lds(
        (const __attribute__((address_space(1))) void*)g,
        (__attribute__((address_space(3))) void*)l, 16, 0, 0);
}
// contiguous: nfloats multiple of 256; 1 inst moves 256 floats (64 lanes x 16B)
__device__ __forceinline__ void stage_contig(const float* g, float* l, int nfloats, int tid) {
    const int lane = tid & 63, wv = tid >> 6;
    const int ninst = nfloats >> 8;
    for (int i = wv; i < ninst; i += 4)
        async_cp16(g + i*256 + lane*4, l + i*256);
}
// 32-col slice of row-major [nrows][ld] at col j0 -> LDS [r][32]
__device__ __forceinline__ void stage_slice32(const float* g, float* l, int ld, int j0, int nrows, int tid) {
    const int lane = tid & 63, wv = tid >> 6;
    const int r = lane >> 3, c4 = (lane & 7) << 2;
    const int ninst = nrows >> 3;
    for (int i = wv; i < ninst; i += 4)
        async_cp16(g + (i*8 + r)*ld + j0 + c4, l + i*256);
}
// 16-col slice of row-major [nrows][ld] at col j0 -> LDS [r][16]
__device__ __forceinline__ void stage_slice16(const float* g, float* l, int ld, int j0, int nrows, int tid) {
    const int lane = tid & 63, wv = tid >> 6;
    const int r = lane >> 2, c4 = (lane & 3) << 2;
    const int ninst = nrows >> 4;
    for (int i = wv; i < ninst; i += 4)
        async_cp16(g + (i*16 + r)*ld + j0 + c4, l + i*256);
}

#define SPIN_GUARD (1u << 22)
__device__ __forceinline__ void wait_cnt(unsigned int* p, unsigned int target) {
    unsigned int g = 0;
    while (__hip_atomic_load(p, __ATOMIC_ACQUIRE, __HIP_MEMORY_SCOPE_AGENT) < target) {
        if (++g > SPIN_GUARD) break;     // bounded: no hang (absmax catches it)
    }
}

__global__ __launch_bounds__(256) void mega(
    const float* __restrict__ positions, const float* __restrict__ grid_pts,
    const float* __restrict__ W1, const float* __restrict__ b1,
    const float* __restrict__ W2, const float* __restrict__ b2,
    const float* __restrict__ W3, const float* __restrict__ b3,
    const float* __restrict__ Wn1, const float* __restrict__ bn1,
    const float* __restrict__ Wn2, const float* __restrict__ bn2,
    const float* __restrict__ Wh1, const float* __restrict__ bh1,
    const float* __restrict__ Wh2, const float* __restrict__ bh2,
    float* __restrict__ gf_ws, float* __restrict__ tpart_ws,
    float* __restrict__ agg_ws, float* __restrict__ h1h_ws,
    unsigned int* __restrict__ cnts, float* __restrict__ out)
{
    const int tid = threadIdx.x;
    const int blk = blockIdx.x;

    // ================= level 0: gf (blocks 0..63) — verbatim K1a ==========
    if (blk < 64) {
        __shared__ __align__(16) float w3s[128*32];         // 16 KB slice
        __shared__ float pos_s[192], grid_s[192], w1_s[192], b1_s[64];
        __shared__ int   idx_s[64], win_s[8];
        __shared__ __align__(16) float h1s[8*64];
        __shared__ __align__(16) float h2s[8*128];

        const int bg = blk >> 3;       // rows bg*8 .. bg*8+7 (replicated x8)
        const int j0 = (blk & 7) * 32; // own 32 output cols

        if (tid < 192) { pos_s[tid] = positions[tid]; grid_s[tid] = grid_pts[tid]; w1_s[tid] = W1[tid]; }
        if (tid >= 192) b1_s[tid - 192] = b1[tid - 192];
        const float bb2 = b2[tid & 127];
        __syncthreads();                                    // small LDS only

        stage_slice32(W3, w3s, 256, j0, 128, tid);          // drains at next sync,
                                                            // overlapped w/ argmin
        if (tid < 64) {                  // verbatim argmin
            const float px = pos_s[tid*3], py = pos_s[tid*3+1], pz = pos_s[tid*3+2];
            float best = 3.4e38f; int bi = 0;
            for (int g = 0; g < 64; ++g) {
                const float dx = px - grid_s[g*3];
                const float dy = py - grid_s[g*3+1];
                const float dz = pz - grid_s[g*3+2];
                const float d2 = dx*dx + dy*dy + dz*dz;
                if (d2 < best) { best = d2; bi = g; }
            }
            idx_s[tid] = bi;
        }
        __syncthreads();
        if (tid < 8) {                   // verbatim winner rule, own 8 rows
            const int g = bg*8 + tid;
            int m = -1;
            for (int i = 0; i < 64; ++i) if (idx_s[i] == g) m = i;
            win_s[tid] = m;
        }
        __syncthreads();

        // h1 own 8 rows (512 outs): verbatim expression
        #pragma unroll
        for (int u = 0; u < 2; ++u) {
            const int e  = tid + u*256;
            const int lr = e >> 6, kk = e & 63;
            int r = win_s[lr]; if (r < 0) r = 0;
            const float acc = b1_s[kk] + pos_s[r*3]*w1_s[kk] + pos_s[r*3+1]*w1_s[64+kk]
                                       + pos_s[r*3+2]*w1_s[128+kk];
            h1s[lr*64 + kk] = fmaxf(acc, 0.f);
        }
        __syncthreads();

        // h2 own 8 rows: verbatim chunk structure; W2 via chunked GLOBAL loads
        {
            const int d = tid & 127, t0 = tid >> 7;
            float acc[4];
            #pragma unroll
            for (int m = 0; m < 4; ++m) acc[m] = bb2;
            for (int kc = 0; kc < 64; kc += 16) {
                float w[16];
                #pragma unroll
                for (int u = 0; u < 16; ++u) w[u] = W2[(kc+u)*128 + d];
                #pragma unroll
                for (int u = 0; u < 16; u += 4) {
                    #pragma unroll
                    for (int m = 0; m < 4; ++m) {
                        const float4 h4 = *(const float4*)&h1s[(t0 + 2*m)*64 + kc + u];
                        acc[m] += h4.x*w[u] + h4.y*w[u+1] + h4.z*w[u+2] + h4.w*w[u+3];
                    }
                }
            }
            #pragma unroll
            for (int m = 0; m < 4; ++m)
                h2s[(t0 + 2*m)*128 + d] = fmaxf(acc[m], 0.f);
        }
        __syncthreads();

        // gf: one output (t, j0+jl) per thread; per-output chain VERBATIM
        {
            const int t = tid >> 5, jl = tid & 31;
            float ag = 0.f;
            for (int dc = 0; dc < 128; dc += 16) {
                float w[16];
                #pragma unroll
                for (int u = 0; u < 16; ++u) w[u] = w3s[(dc+u)*32 + jl];
                #pragma unroll
                for (int u = 0; u < 16; u += 4) {
                    const float4 h4 = *(const float4*)&h2s[t*128 + dc + u];
                    ag += h4.x*w[u] + h4.y*w[u+1] + h4.z*w[u+2] + h4.w*w[u+3];
                }
            }
            const float bb3 = b3[j0 + jl];
            gf_ws[(bg*8 + t)*256 + j0 + jl] = (win_s[t] >= 0) ? (ag + bb3) : 0.f;
        }
        __threadfence();                 // release gf stores device-wide
        __syncthreads();
        if (tid == 0)
            __hip_atomic_fetch_add(&cnts[0], 1u, __ATOMIC_RELEASE, __HIP_MEMORY_SCOPE_AGENT);
        return;
    }

    // ================= level 1: tpart (blocks 64..191) — verbatim K1b =====
    if (blk < 192) {
        __shared__ __align__(16) float wn1_s[256*16];       // 16 KB slice
        __shared__ __align__(16) float gf_s[8*256];
        __shared__ float r_s[128];

        const int b2i = blk - 64;
        const int bg  = b2i >> 4;
        const int j0  = (b2i & 15) * 16;
        stage_slice16(Wn1, wn1_s, 256, j0, 256, tid);       // AT ENTRY: overlaps gf

        if (tid == 0) wait_cnt(&cnts[0], 64u);              // gf_ws ready
        __syncthreads();                                    // (drains wn1 too)
        stage_contig(gf_ws + bg*8*256, gf_s, 8*256, tid);

        const int jl = tid & 15, t = tid >> 4;
        const float bb = bn1[j0 + jl];
        __syncthreads();                                    // drain gf stage

        if (t < 8) {   // per-output (row t, col j0+jl) chain VERBATIM
            float acc = bb;
            for (int cc = 0; cc < 256; cc += 32) {
                float w[32];
                #pragma unroll
                for (int u = 0; u < 32; ++u) w[u] = wn1_s[(cc+u)*16 + jl];
                #pragma unroll
                for (int u = 0; u < 32; u += 4) {
                    const float4 g4 = *(const float4*)&gf_s[t*256 + cc + u];
                    acc += g4.x*w[u] + g4.y*w[u+1] + g4.z*w[u+2] + g4.w*w[u+3];
                }
            }
            r_s[t*16 + jl] = fmaxf(acc, 0.f);
        }
        __syncthreads();
        if (t == 0) {   // verbatim tt 0..7 ascending
            float ps = 0.f;
            #pragma unroll
            for (int tt = 0; tt < 8; ++tt) ps += r_s[tt*16 + jl];
            tpart_ws[bg*256 + j0 + jl] = ps;
        }
        __threadfence();
        __syncthreads();
        if (tid == 0)
            __hip_atomic_fetch_add(&cnts[1], 1u, __ATOMIC_RELEASE, __HIP_MEMORY_SCOPE_AGENT);
        return;
    }

    // ================= level 2: agg (blocks 192..223) — verbatim K2 =======
    if (blk < 224) {
        __shared__ __align__(16) float wn2_s[256*8];        // 8 KB col-slice
        __shared__ __align__(16) float tp_s[2048];
        __shared__ __align__(16) float tbar_s[256];

        const int j0a = (blk - 192) * 8;

        {   // Wn2 col-slice AT ENTRY: overlaps gf+tpart upstream
            const int lane = tid & 63, wv = tid >> 6;
            const int r = lane >> 1, c4 = (lane & 1) << 2;
            for (int i = wv; i < 8; i += 4)
                async_cp16(Wn2 + (i*32 + r)*256 + j0a + c4, wn2_s + i*256);
        }
        if (tid == 0) wait_cnt(&cnts[1], 128u);             // tpart_ws ready
        __syncthreads();                                    // (drains wn2 too)
        stage_contig(tpart_ws, tp_s, 2048, tid);
        __syncthreads();                                    // drain tp stage

        {   // tbar: verbatim (q ascending, then *1/64)
            float tb = 0.f;
            #pragma unroll
            for (int q = 0; q < 8; ++q) tb += tp_s[q*256 + tid];
            tbar_s[tid] = tb * (1.f/64.f);
        }
        __syncthreads();

        if (tid < 8) {   // agg outputs j0a..j0a+7: verbatim chunk order
            float acc = bn2[j0a + tid];
            for (int jc = 0; jc < 256; jc += 32) {
                float w[32];
                #pragma unroll
                for (int u = 0; u < 32; ++u) w[u] = wn2_s[(jc+u)*8 + tid];
                #pragma unroll
                for (int u = 0; u < 32; u += 4) {
                    const float4 t4 = *(const float4*)&tbar_s[jc + u];
                    acc += t4.x*w[u] + t4.y*w[u+1] + t4.z*w[u+2] + t4.w*w[u+3];
                }
            }
            agg_ws[j0a + tid] = acc;
        }
        __threadfence();
        __syncthreads();
        if (tid == 0)
            __hip_atomic_fetch_add(&cnts[2], 1u, __ATOMIC_RELEASE, __HIP_MEMORY_SCOPE_AGENT);
        return;
    }

    // ================= level 3: heads (blocks 224..239) — verbatim K34 ====
    {
        __shared__ __align__(16) float whs[256*32];         // 32 KB slice
        __shared__ __align__(16) float agg_s[256];
        __shared__ int last_s;

        const int hb = blk - 224;
        const int k  = hb >> 2;
        const int d0 = (hb & 3) * 32;

        stage_slice32(Wh1 + k*32768, whs, 128, d0, 256, tid);  // AT ENTRY
        if (tid == 0) wait_cnt(&cnts[2], 32u);              // agg_ws ready
        __syncthreads();                                    // (drains whs too)
        agg_s[tid] = agg_ws[tid];
        __syncthreads();

        if (tid < 32) {   // per-output cc-chain VERBATIM (cc ascending 0..255)
            const int dl = tid;
            float a = bh1[k*128 + d0 + dl];
            for (int cc = 0; cc < 256; cc += 16) {
                float wa[16];
                #pragma unroll
                for (int u = 0; u < 16; ++u) wa[u] = whs[(cc+u)*32 + dl];
                #pragma unroll
                for (int u = 0; u < 16; u += 4) {
                    const float4 a4 = *(const float4*)&agg_s[cc + u];
                    a += a4.x*wa[u] + a4.y*wa[u+1] + a4.z*wa[u+2] + a4.w*wa[u+3];
                }
            }
            h1h_ws[k*128 + d0 + dl] = fmaxf(a, 0.f);
        }
        __threadfence();                 // release h1h stores device-wide
        __syncthreads();                 // all threads' fences complete
        if (tid == 0) {
            const unsigned old = __hip_atomic_fetch_add(
                &cnts[3], 1u, __ATOMIC_ACQ_REL, __HIP_MEMORY_SCOPE_AGENT);
            last_s = (old == 15u) ? 1 : 0;   // last arriver, no spinning
        }
        __syncthreads();
        if (last_s && tid < 4) {         // verbatim strictly-sequential dots
            const int kk = tid;
            float a = bh2[kk];
            for (int d = 0; d < 128; ++d)
                a += h1h_ws[kk*128 + d] * Wh2[kk*128 + d];
            out[kk] = a;
        }
    }
}

extern "C" void kernel_launch(void* const* d_in, const int* in_sizes, int n_in,
                              void* d_out, int out_size, void* d_ws, size_t ws_size,
                              hipStream_t stream) {
    const float* positions = (const float*)d_in[0];
    const float* grid      = (const float*)d_in[1];
    const float* W1  = (const float*)d_in[2];
    const float* b1  = (const float*)d_in[3];
    const float* W2  = (const float*)d_in[4];
    const float* b2  = (const float*)d_in[5];
    const float* W3  = (const float*)d_in[6];
    const float* b3  = (const float*)d_in[7];
    const float* Wn1 = (const float*)d_in[8];
    const float* bn1 = (const float*)d_in[9];
    const float* Wn2 = (const float*)d_in[10];
    const float* bn2 = (const float*)d_in[11];
    const float* Wh1 = (const float*)d_in[12];
    const float* bh1 = (const float*)d_in[13];
    const float* Wh2 = (const float*)d_in[14];
    const float* bh2 = (const float*)d_in[15];
    float* outp = (float*)d_out;

    char* ws = (char*)d_ws;                 // fully rewritten every call
    float* gf_ws    = (float*)(ws + 0);          // 64*256 f = 64 KB
    float* tpart_ws = (float*)(ws + 65536);      // 8*256 f = 8 KB
    float* agg_ws   = (float*)(ws + 73728);      // 256 f = 1 KB
    float* h1h_ws   = (float*)(ws + 74752);      // 4*128 f = 2 KB
    unsigned int* cnts = (unsigned int*)(ws + 76800);  // 4 counters

    (void)hipMemsetAsync((void*)cnts, 0, 16, stream);  // zero counters per-iter

    hipLaunchKernelGGL(mega, dim3(240), dim3(256), 0, stream,
                       positions, grid, W1, b1, W2, b2, W3, b3,
                       Wn1, bn1, Wn2, bn2, Wh1, bh1, Wh2, bh2,
                       gf_ws, tpart_ws, agg_ws, h1h_ws, cnts, outp);
}

// Round 8
// 106.444 us; speedup vs baseline: 1.4142x; 1.4142x over previous
//
#include <hip/hip_runtime.h>

// ---------------------------------------------------------------------------
// Output depends ONLY on positions[0:64]. ~14M MACs total.
//
// R16 = R14 (proven 104.1us, absmax 0.0) + 128 cache-warm blocks in K1a.
//
// R15 LESSON (measured): in-kernel device-scope spin polling is catastrophic
// on gfx950 — mega kernel ran 73us at 0.85% VALUBusy / 0.3% HBM: acquire
// polls invalidate the non-coherent per-XCD caches continuously, starving
// producers. NEVER poll device memory in-kernel. Kernel boundaries
// (~1-1.5us) are the cheap cross-block sync; zero-spin last-arriver is OK.
//
// Structure (4 dispatches):
//  K1a (192 blk): blk 0..63  = bg x 8 col-slices: backbone replicated +
//                 gf 32-col slice (W3 16KB slice staged post-sync).
//                 blk 64..191 = CACHE-WARM: each reads one 64KB chunk of
//                 Wn1/Wn2/Wh1 (float4, kept live via asm) so every XCD L2
//                 holds all downstream weights before K1b/K2/K34 run.
//                 Round-robin blk->XCD puts one block per (XCD, chunk).
//  K1b (128 blk = bg x 16 col-slices): tpart, Wn1 16-col slices. Verbatim.
//  K2  (32 blk): tbar + agg 8-col slice; block0 zeroes K34 counter. Verbatim.
//  K34 (16 blk = 4 heads x 4 d-slices): heads h1; last-arriver (one acq_rel
//                 fetch_add, NO loop) computes the 4 final dots. Verbatim.
//
// BIT-EXACTNESS: harness demands bit-exact (R1 failed by one ulp). Every
// per-output accumulation keeps the VERBATIM expression structure and
// ascending chunk order from rounds that scored absmax 0.0. Warm blocks
// write NOTHING. Do not reassociate; do not regroup.
// ---------------------------------------------------------------------------

__device__ __forceinline__ void async_cp16(const float* g, float* l) {
    __builtin_amdgcn_global_load_lds(
        (const __attribute__((address_space(1))) void*)g,
        (__attribute__((address_space(3))) void*)l, 16, 0, 0);
}
// contiguous: nfloats multiple of 256; 1 inst moves 256 floats (64 lanes x 16B)
__device__ __forceinline__ void stage_contig(const float* g, float* l, int nfloats, int tid) {
    const int lane = tid & 63, wv = tid >> 6;
    const int ninst = nfloats >> 8;
    for (int i = wv; i < ninst; i += 4)
        async_cp16(g + i*256 + lane*4, l + i*256);
}
// 32-col slice of row-major [nrows][ld] at col j0 -> LDS [r][32]
__device__ __forceinline__ void stage_slice32(const float* g, float* l, int ld, int j0, int nrows, int tid) {
    const int lane = tid & 63, wv = tid >> 6;
    const int r = lane >> 3, c4 = (lane & 7) << 2;
    const int ninst = nrows >> 3;
    for (int i = wv; i < ninst; i += 4)
        async_cp16(g + (i*8 + r)*ld + j0 + c4, l + i*256);
}
// 16-col slice of row-major [nrows][ld] at col j0 -> LDS [r][16]
__device__ __forceinline__ void stage_slice16(const float* g, float* l, int ld, int j0, int nrows, int tid) {
    const int lane = tid & 63, wv = tid >> 6;
    const int r = lane >> 2, c4 = (lane & 3) << 2;
    const int ninst = nrows >> 4;
    for (int i = wv; i < ninst; i += 4)
        async_cp16(g + (i*16 + r)*ld + j0 + c4, l + i*256);
}

// ---- K1a (192 blocks): 64 worker (backbone + gf slice) + 128 cache-warm ---
__global__ __launch_bounds__(256) void k1a_gf(
    const float* __restrict__ positions, const float* __restrict__ grid_pts,
    const float* __restrict__ W1, const float* __restrict__ b1,
    const float* __restrict__ W2, const float* __restrict__ b2,
    const float* __restrict__ W3, const float* __restrict__ b3,
    const float* __restrict__ Wn1, const float* __restrict__ Wn2,
    const float* __restrict__ Wh1,
    float* __restrict__ gf_ws)                              // (64,256)
{
    const int tid = threadIdx.x;
    const int blk = blockIdx.x;

    if (blk >= 64) {                     // -------- cache-warm blocks -------
        // w=blk-64 in 0..127; chunk c=w>>3 in 0..15 (64KB each). The 8 blocks
        // sharing chunk c have consecutive blk -> one per XCD (round-robin),
        // so every XCD L2 ends up holding all 16 chunks (Wn1+Wn2+Wh1, 1MB).
        const int w = blk - 64;
        const int c = w >> 3;
        const float* src = (c < 4) ? (Wn1 + c*16384)
                         : (c < 8) ? (Wn2 + (c-4)*16384)
                                   : (Wh1 + (c-8)*16384);
        const float4* p = (const float4*)src + tid;
        float sx = 0.f, sy = 0.f, sz = 0.f, sw = 0.f;
        #pragma unroll
        for (int i = 0; i < 16; ++i) {
            const float4 v = p[i*256];
            sx += v.x; sy += v.y; sz += v.z; sw += v.w;
        }
        asm volatile("" :: "v"(sx), "v"(sy), "v"(sz), "v"(sw));  // keep loads live
        return;
    }

    __shared__ __align__(16) float w3s[128*32];             // 16 KB slice
    __shared__ float pos_s[192], grid_s[192], w1_s[192], b1_s[64];
    __shared__ int   idx_s[64], win_s[8];
    __shared__ __align__(16) float h1s[8*64];
    __shared__ __align__(16) float h2s[8*128];

    const int bg  = blk >> 3;          // rows bg*8 .. bg*8+7 (replicated x8)
    const int j0  = (blk & 7) * 32;    // own 32 output cols

    if (tid < 192) { pos_s[tid] = positions[tid]; grid_s[tid] = grid_pts[tid]; w1_s[tid] = W1[tid]; }
    if (tid >= 192) b1_s[tid - 192] = b1[tid - 192];
    const float bb2 = b2[tid & 127];
    __syncthreads();                                        // small LDS only

    stage_slice32(W3, w3s, 256, j0, 128, tid);              // drains at next sync,
                                                            // overlapped w/ argmin
    if (tid < 64) {                      // verbatim argmin
        const float px = pos_s[tid*3], py = pos_s[tid*3+1], pz = pos_s[tid*3+2];
        float best = 3.4e38f; int bi = 0;
        for (int g = 0; g < 64; ++g) {
            const float dx = px - grid_s[g*3];
            const float dy = py - grid_s[g*3+1];
            const float dz = pz - grid_s[g*3+2];
            const float d2 = dx*dx + dy*dy + dz*dz;
            if (d2 < best) { best = d2; bi = g; }
        }
        idx_s[tid] = bi;
    }
    __syncthreads();
    if (tid < 8) {                       // verbatim winner rule, own 8 rows
        const int g = bg*8 + tid;
        int m = -1;
        for (int i = 0; i < 64; ++i) if (idx_s[i] == g) m = i;
        win_s[tid] = m;
    }
    __syncthreads();

    // h1 own 8 rows (512 outs): verbatim expression
    #pragma unroll
    for (int u = 0; u < 2; ++u) {
        const int e  = tid + u*256;
        const int lr = e >> 6, kk = e & 63;
        int r = win_s[lr]; if (r < 0) r = 0;
        const float acc = b1_s[kk] + pos_s[r*3]*w1_s[kk] + pos_s[r*3+1]*w1_s[64+kk]
                                   + pos_s[r*3+2]*w1_s[128+kk];
        h1s[lr*64 + kk] = fmaxf(acc, 0.f);
    }
    __syncthreads();

    // h2 own 8 rows: verbatim chunk structure; W2 via chunked GLOBAL loads
    {
        const int d = tid & 127, t0 = tid >> 7;
        float acc[4];
        #pragma unroll
        for (int m = 0; m < 4; ++m) acc[m] = bb2;
        for (int kc = 0; kc < 64; kc += 16) {
            float w[16];
            #pragma unroll
            for (int u = 0; u < 16; ++u) w[u] = W2[(kc+u)*128 + d];
            #pragma unroll
            for (int u = 0; u < 16; u += 4) {
                #pragma unroll
                for (int m = 0; m < 4; ++m) {
                    const float4 h4 = *(const float4*)&h1s[(t0 + 2*m)*64 + kc + u];
                    acc[m] += h4.x*w[u] + h4.y*w[u+1] + h4.z*w[u+2] + h4.w*w[u+3];
                }
            }
        }
        #pragma unroll
        for (int m = 0; m < 4; ++m)
            h2s[(t0 + 2*m)*128 + d] = fmaxf(acc[m], 0.f);
    }
    __syncthreads();

    // gf: one output (t, j0+jl) per thread; per-output chain VERBATIM
    {
        const int t = tid >> 5, jl = tid & 31;
        float ag = 0.f;
        for (int dc = 0; dc < 128; dc += 16) {
            float w[16];
            #pragma unroll
            for (int u = 0; u < 16; ++u) w[u] = w3s[(dc+u)*32 + jl];
            #pragma unroll
            for (int u = 0; u < 16; u += 4) {
                const float4 h4 = *(const float4*)&h2s[t*128 + dc + u];
                ag += h4.x*w[u] + h4.y*w[u+1] + h4.z*w[u+2] + h4.w*w[u+3];
            }
        }
        const float bb3 = b3[j0 + jl];
        gf_ws[(bg*8 + t)*256 + j0 + jl] = (win_s[t] >= 0) ? (ag + bb3) : 0.f;
    }
}

// ---- K1b (128 blocks = bg x 16 col-slices): Wn1-slice tpart --------------
__global__ __launch_bounds__(256) void k1b_tpart(
    const float* __restrict__ Wn1, const float* __restrict__ bn1,
    const float* __restrict__ gf_ws, float* __restrict__ tpart_ws)
{
    __shared__ __align__(16) float wn1_s[256*16];           // 16 KB slice
    __shared__ __align__(16) float gf_s[8*256];
    __shared__ float r_s[128];

    const int tid = threadIdx.x;
    const int bg  = blockIdx.x >> 4;
    const int j0  = (blockIdx.x & 15) * 16;
    stage_slice16(Wn1, wn1_s, 256, j0, 256, tid);
    stage_contig(gf_ws + bg*8*256, gf_s, 8*256, tid);

    const int jl = tid & 15, t = tid >> 4;                  // t in 0..15, rows use t<8
    const float bb = bn1[j0 + jl];
    __syncthreads();

    if (t < 8) {   // per-output (row t, col j0+jl) chain VERBATIM
        float acc = bb;
        for (int cc = 0; cc < 256; cc += 32) {
            float w[32];
            #pragma unroll
            for (int u = 0; u < 32; ++u) w[u] = wn1_s[(cc+u)*16 + jl];
            #pragma unroll
            for (int u = 0; u < 32; u += 4) {
                const float4 g4 = *(const float4*)&gf_s[t*256 + cc + u];
                acc += g4.x*w[u] + g4.y*w[u+1] + g4.z*w[u+2] + g4.w*w[u+3];
            }
        }
        r_s[t*16 + jl] = fmaxf(acc, 0.f);
    }
    __syncthreads();
    if (t == 0) {   // verbatim tt 0..7 ascending
        float ps = 0.f;
        #pragma unroll
        for (int tt = 0; tt < 8; ++tt) ps += r_s[tt*16 + jl];
        tpart_ws[bg*256 + j0 + jl] = ps;
    }
}

// ---- K2 (32 blocks): tbar + agg 8-col slice (proven bit-exact) -----------
__global__ __launch_bounds__(256) void k2_agg(
    const float* __restrict__ Wn2, const float* __restrict__ bn2,
    const float* __restrict__ tpart_ws, float* __restrict__ agg_ws,
    unsigned int* __restrict__ cnts)
{
    __shared__ __align__(16) float wn2_s[256*8];            // 8 KB col-slice
    __shared__ __align__(16) float tp_s[2048];
    __shared__ __align__(16) float tbar_s[256];

    const int tid = threadIdx.x;
    const int j0a = blockIdx.x * 8;

    if (blockIdx.x == 0 && tid == 0) cnts[0] = 0u;          // K34 counter; 1 full
                                                            // boundary downstream
    {   // Wn2 col-slice [256 rows][8 cols] at j0a -> wn2_s[r*8 + c]
        const int lane = tid & 63, wv = tid >> 6;
        const int r = lane >> 1, c4 = (lane & 1) << 2;
        for (int i = wv; i < 8; i += 4)
            async_cp16(Wn2 + (i*32 + r)*256 + j0a + c4, wn2_s + i*256);
    }
    stage_contig(tpart_ws, tp_s, 2048, tid);
    __syncthreads();

    {   // tbar: verbatim (q ascending, then *1/64)
        float tb = 0.f;
        #pragma unroll
        for (int q = 0; q < 8; ++q) tb += tp_s[q*256 + tid];
        tbar_s[tid] = tb * (1.f/64.f);
    }
    __syncthreads();

    if (tid < 8) {   // agg outputs j0a..j0a+7: verbatim chunk order
        float acc = bn2[j0a + tid];
        for (int jc = 0; jc < 256; jc += 32) {
            float w[32];
            #pragma unroll
            for (int u = 0; u < 32; ++u) w[u] = wn2_s[(jc+u)*8 + tid];
            #pragma unroll
            for (int u = 0; u < 32; u += 4) {
                const float4 t4 = *(const float4*)&tbar_s[jc + u];
                acc += t4.x*w[u] + t4.y*w[u+1] + t4.z*w[u+2] + t4.w*w[u+3];
            }
        }
        agg_ws[j0a + tid] = acc;
    }
}

// ---- K34 (16 blocks = 4 heads x 4 d-slices): heads h1 + last-arriver out --
__global__ __launch_bounds__(256) void k34_h1out(
    const float* __restrict__ Wh1, const float* __restrict__ bh1,
    const float* __restrict__ Wh2, const float* __restrict__ bh2,
    const float* __restrict__ agg_ws, float* __restrict__ h1h_ws,
    unsigned int* __restrict__ cnts, float* __restrict__ out)
{
    __shared__ __align__(16) float whs[256*32];             // 32 KB slice
    __shared__ __align__(16) float agg_s[256];
    __shared__ int last_s;

    const int tid = threadIdx.x;
    const int k   = blockIdx.x >> 2;
    const int d0  = (blockIdx.x & 3) * 32;

    stage_slice32(Wh1 + k*32768, whs, 128, d0, 256, tid);
    agg_s[tid] = agg_ws[tid];
    __syncthreads();                                        // drains both

    if (tid < 32) {   // per-output cc-chain VERBATIM (cc ascending 0..255)
        const int dl = tid;
        float a = bh1[k*128 + d0 + dl];
        for (int cc = 0; cc < 256; cc += 16) {
            float wa[16];
            #pragma unroll
            for (int u = 0; u < 16; ++u) wa[u] = whs[(cc+u)*32 + dl];
            #pragma unroll
            for (int u = 0; u < 16; u += 4) {
                const float4 a4 = *(const float4*)&agg_s[cc + u];
                a += a4.x*wa[u] + a4.y*wa[u+1] + a4.z*wa[u+2] + a4.w*wa[u+3];
            }
        }
        h1h_ws[k*128 + d0 + dl] = fmaxf(a, 0.f);
    }
    __threadfence();                     // release h1h stores device-wide
    __syncthreads();                     // all threads' fences complete
    if (tid == 0) {
        const unsigned old = __hip_atomic_fetch_add(
            &cnts[0], 1u, __ATOMIC_ACQ_REL, __HIP_MEMORY_SCOPE_AGENT);
        last_s = (old == 15u) ? 1 : 0;   // last arriver, NO spinning
    }
    __syncthreads();
    if (last_s && tid < 4) {             // verbatim strictly-sequential dots
        const int kk = tid;
        float a = bh2[kk];
        for (int d = 0; d < 128; ++d)
            a += h1h_ws[kk*128 + d] * Wh2[kk*128 + d];
        out[kk] = a;
    }
}

extern "C" void kernel_launch(void* const* d_in, const int* in_sizes, int n_in,
                              void* d_out, int out_size, void* d_ws, size_t ws_size,
                              hipStream_t stream) {
    const float* positions = (const float*)d_in[0];
    const float* grid      = (const float*)d_in[1];
    const float* W1  = (const float*)d_in[2];
    const float* b1  = (const float*)d_in[3];
    const float* W2  = (const float*)d_in[4];
    const float* b2  = (const float*)d_in[5];
    const float* W3  = (const float*)d_in[6];
    const float* b3  = (const float*)d_in[7];
    const float* Wn1 = (const float*)d_in[8];
    const float* bn1 = (const float*)d_in[9];
    const float* Wn2 = (const float*)d_in[10];
    const float* bn2 = (const float*)d_in[11];
    const float* Wh1 = (const float*)d_in[12];
    const float* bh1 = (const float*)d_in[13];
    const float* Wh2 = (const float*)d_in[14];
    const float* bh2 = (const float*)d_in[15];
    float* out = (float*)d_out;

    char* ws = (char*)d_ws;                 // fully rewritten every call
    float* gf_ws    = (float*)(ws + 0);          // 64*256 f = 64 KB
    float* tpart_ws = (float*)(ws + 65536);      // 8*256 f = 8 KB
    float* agg_ws   = (float*)(ws + 73728);      // 256 f = 1 KB
    float* h1h_ws   = (float*)(ws + 74752);      // 4*128 f = 2 KB
    unsigned int* cnts = (unsigned int*)(ws + 76800);

    hipLaunchKernelGGL(k1a_gf,    dim3(192), dim3(256), 0, stream,
                       positions, grid, W1, b1, W2, b2, W3, b3,
                       Wn1, Wn2, Wh1, gf_ws);
    hipLaunchKernelGGL(k1b_tpart, dim3(128), dim3(256), 0, stream,
                       Wn1, bn1, gf_ws, tpart_ws);
    hipLaunchKernelGGL(k2_agg,    dim3(32),  dim3(256), 0, stream,
                       Wn2, bn2, tpart_ws, agg_ws, cnts);
    hipLaunchKernelGGL(k34_h1out, dim3(16),  dim3(256), 0, stream,
                       Wh1, bh1, Wh2, bh2, agg_ws, h1h_ws, cnts, out);
}

// Round 9
// 104.132 us; speedup vs baseline: 1.4456x; 1.0222x over previous
//
#include <hip/hip_runtime.h>

// ---------------------------------------------------------------------------
// Output depends ONLY on positions[0:64]. ~14M MACs total.
//
// R17 = R14 verbatim (best measured: 104.13us, absmax 0.0). Reverts R16's
// cache-warm blocks (+2.3us: warm blocks extended K1a's tail + HBM
// contention > L2-warmth savings).
//
// ACCUMULATED EVIDENCE (do not retry):
//  - R10: fusing kernels (3->2) = +-0. Kernel boundaries ~1.5us each.
//  - R11: in-kernel spin barriers = +4.5us.
//  - R15: producer/consumer mega-kernel with acquire-polling = +46us
//    (0.85% VALUBusy: agent-scope acquire polls thrash non-coherent
//    per-XCD caches). NEVER poll device memory in-kernel on gfx950.
//  - R16: cache-warm helper blocks = +2.3us (tail extension + contention).
//  - R12->R14: smaller per-CU staging + fewer boundaries = the only wins.
// Structure: 81us harness poison-fills (fixed) + ~10us staging/compute +
// ~13us dispatch overhead. This is the dispatch-overhead floor.
//
// 4 dispatches:
//  K1a (64 blk = bg x 8 col-slices): backbone replicated + gf 32-col slice.
//      W3 stage issued AFTER the first sync so its drain overlaps argmin.
//  K1b (128 blk = bg x 16 col-slices): tpart with 16-col Wn1 slices.
//  K2  (32 blk): tbar + agg 8-col slice; block0 zeroes the K34 counter
//      (1 kernel boundary upstream of use -> visible).
//  K34 (16 blk = 4 heads x 4 d-slices): heads h1; last-arriver (ONE acq_rel
//      fetch_add, NO loop) computes the 4 final strictly-sequential dots.
//
// BIT-EXACTNESS: harness demands bit-exact (R1 failed by one ulp). Every
// per-output accumulation keeps the VERBATIM expression structure and
// ascending chunk order from rounds that scored absmax 0.0. Splits are only
// along data-parallel output dims; reduction orders (8-row groups, q 0..7,
// tt 0..7, cc/dc/jc ascending, final d 0..127 sequential) unchanged.
// f32 global round-trips are lossless. Do not reassociate; do not regroup.
// ---------------------------------------------------------------------------

__device__ __forceinline__ void async_cp16(const float* g, float* l) {
    __builtin_amdgcn_global_load_lds(
        (const __attribute__((address_space(1))) void*)g,
        (__attribute__((address_space(3))) void*)l, 16, 0, 0);
}
// contiguous: nfloats multiple of 256; 1 inst moves 256 floats (64 lanes x 16B)
__device__ __forceinline__ void stage_contig(const float* g, float* l, int nfloats, int tid) {
    const int lane = tid & 63, wv = tid >> 6;
    const int ninst = nfloats >> 8;
    for (int i = wv; i < ninst; i += 4)
        async_cp16(g + i*256 + lane*4, l + i*256);
}
// 32-col slice of row-major [nrows][ld] at col j0 -> LDS [r][32]
__device__ __forceinline__ void stage_slice32(const float* g, float* l, int ld, int j0, int nrows, int tid) {
    const int lane = tid & 63, wv = tid >> 6;
    const int r = lane >> 3, c4 = (lane & 7) << 2;
    const int ninst = nrows >> 3;
    for (int i = wv; i < ninst; i += 4)
        async_cp16(g + (i*8 + r)*ld + j0 + c4, l + i*256);
}
// 16-col slice of row-major [nrows][ld] at col j0 -> LDS [r][16]
__device__ __forceinline__ void stage_slice16(const float* g, float* l, int ld, int j0, int nrows, int tid) {
    const int lane = tid & 63, wv = tid >> 6;
    const int r = lane >> 2, c4 = (lane & 3) << 2;
    const int ninst = nrows >> 4;
    for (int i = wv; i < ninst; i += 4)
        async_cp16(g + (i*16 + r)*ld + j0 + c4, l + i*256);
}

// ---- K1a (64 blocks = 8 row-groups x 8 col-slices): backbone + gf slice ---
__global__ __launch_bounds__(256) void k1a_gf(
    const float* __restrict__ positions, const float* __restrict__ grid_pts,
    const float* __restrict__ W1, const float* __restrict__ b1,
    const float* __restrict__ W2, const float* __restrict__ b2,
    const float* __restrict__ W3, const float* __restrict__ b3,
    float* __restrict__ gf_ws)                              // (64,256)
{
    __shared__ __align__(16) float w3s[128*32];             // 16 KB slice
    __shared__ float pos_s[192], grid_s[192], w1_s[192], b1_s[64];
    __shared__ int   idx_s[64], win_s[8];
    __shared__ __align__(16) float h1s[8*64];
    __shared__ __align__(16) float h2s[8*128];

    const int tid = threadIdx.x;
    const int blk = blockIdx.x;
    const int bg  = blk >> 3;          // rows bg*8 .. bg*8+7 (replicated x8)
    const int j0  = (blk & 7) * 32;    // own 32 output cols

    if (tid < 192) { pos_s[tid] = positions[tid]; grid_s[tid] = grid_pts[tid]; w1_s[tid] = W1[tid]; }
    if (tid >= 192) b1_s[tid - 192] = b1[tid - 192];
    const float bb2 = b2[tid & 127];
    __syncthreads();                                        // small LDS only

    stage_slice32(W3, w3s, 256, j0, 128, tid);              // drains at next sync,
                                                            // overlapped w/ argmin
    if (tid < 64) {                      // verbatim argmin
        const float px = pos_s[tid*3], py = pos_s[tid*3+1], pz = pos_s[tid*3+2];
        float best = 3.4e38f; int bi = 0;
        for (int g = 0; g < 64; ++g) {
            const float dx = px - grid_s[g*3];
            const float dy = py - grid_s[g*3+1];
            const float dz = pz - grid_s[g*3+2];
            const float d2 = dx*dx + dy*dy + dz*dz;
            if (d2 < best) { best = d2; bi = g; }
        }
        idx_s[tid] = bi;
    }
    __syncthreads();
    if (tid < 8) {                       // verbatim winner rule, own 8 rows
        const int g = bg*8 + tid;
        int m = -1;
        for (int i = 0; i < 64; ++i) if (idx_s[i] == g) m = i;
        win_s[tid] = m;
    }
    __syncthreads();

    // h1 own 8 rows (512 outs): verbatim expression
    #pragma unroll
    for (int u = 0; u < 2; ++u) {
        const int e  = tid + u*256;
        const int lr = e >> 6, kk = e & 63;
        int r = win_s[lr]; if (r < 0) r = 0;
        const float acc = b1_s[kk] + pos_s[r*3]*w1_s[kk] + pos_s[r*3+1]*w1_s[64+kk]
                                   + pos_s[r*3+2]*w1_s[128+kk];
        h1s[lr*64 + kk] = fmaxf(acc, 0.f);
    }
    __syncthreads();

    // h2 own 8 rows: verbatim chunk structure; W2 via chunked GLOBAL loads
    {
        const int d = tid & 127, t0 = tid >> 7;
        float acc[4];
        #pragma unroll
        for (int m = 0; m < 4; ++m) acc[m] = bb2;
        for (int kc = 0; kc < 64; kc += 16) {
            float w[16];
            #pragma unroll
            for (int u = 0; u < 16; ++u) w[u] = W2[(kc+u)*128 + d];
            #pragma unroll
            for (int u = 0; u < 16; u += 4) {
                #pragma unroll
                for (int m = 0; m < 4; ++m) {
                    const float4 h4 = *(const float4*)&h1s[(t0 + 2*m)*64 + kc + u];
                    acc[m] += h4.x*w[u] + h4.y*w[u+1] + h4.z*w[u+2] + h4.w*w[u+3];
                }
            }
        }
        #pragma unroll
        for (int m = 0; m < 4; ++m)
            h2s[(t0 + 2*m)*128 + d] = fmaxf(acc[m], 0.f);
    }
    __syncthreads();

    // gf: one output (t, j0+jl) per thread; per-output chain VERBATIM
    {
        const int t = tid >> 5, jl = tid & 31;
        float ag = 0.f;
        for (int dc = 0; dc < 128; dc += 16) {
            float w[16];
            #pragma unroll
            for (int u = 0; u < 16; ++u) w[u] = w3s[(dc+u)*32 + jl];
            #pragma unroll
            for (int u = 0; u < 16; u += 4) {
                const float4 h4 = *(const float4*)&h2s[t*128 + dc + u];
                ag += h4.x*w[u] + h4.y*w[u+1] + h4.z*w[u+2] + h4.w*w[u+3];
            }
        }
        const float bb3 = b3[j0 + jl];
        gf_ws[(bg*8 + t)*256 + j0 + jl] = (win_s[t] >= 0) ? (ag + bb3) : 0.f;
    }
}

// ---- K1b (128 blocks = bg x 16 col-slices): Wn1-slice tpart --------------
__global__ __launch_bounds__(256) void k1b_tpart(
    const float* __restrict__ Wn1, const float* __restrict__ bn1,
    const float* __restrict__ gf_ws, float* __restrict__ tpart_ws)
{
    __shared__ __align__(16) float wn1_s[256*16];           // 16 KB slice
    __shared__ __align__(16) float gf_s[8*256];
    __shared__ float r_s[128];

    const int tid = threadIdx.x;
    const int bg  = blockIdx.x >> 4;
    const int j0  = (blockIdx.x & 15) * 16;
    stage_slice16(Wn1, wn1_s, 256, j0, 256, tid);
    stage_contig(gf_ws + bg*8*256, gf_s, 8*256, tid);

    const int jl = tid & 15, t = tid >> 4;                  // t in 0..15, rows use t<8
    const float bb = bn1[j0 + jl];
    __syncthreads();

    if (t < 8) {   // per-output (row t, col j0+jl) chain VERBATIM
        float acc = bb;
        for (int cc = 0; cc < 256; cc += 32) {
            float w[32];
            #pragma unroll
            for (int u = 0; u < 32; ++u) w[u] = wn1_s[(cc+u)*16 + jl];
            #pragma unroll
            for (int u = 0; u < 32; u += 4) {
                const float4 g4 = *(const float4*)&gf_s[t*256 + cc + u];
                acc += g4.x*w[u] + g4.y*w[u+1] + g4.z*w[u+2] + g4.w*w[u+3];
            }
        }
        r_s[t*16 + jl] = fmaxf(acc, 0.f);
    }
    __syncthreads();
    if (t == 0) {   // verbatim tt 0..7 ascending
        float ps = 0.f;
        #pragma unroll
        for (int tt = 0; tt < 8; ++tt) ps += r_s[tt*16 + jl];
        tpart_ws[bg*256 + j0 + jl] = ps;
    }
}

// ---- K2 (32 blocks): tbar + agg 8-col slice (proven bit-exact) -----------
__global__ __launch_bounds__(256) void k2_agg(
    const float* __restrict__ Wn2, const float* __restrict__ bn2,
    const float* __restrict__ tpart_ws, float* __restrict__ agg_ws,
    unsigned int* __restrict__ cnts)
{
    __shared__ __align__(16) float wn2_s[256*8];            // 8 KB col-slice
    __shared__ __align__(16) float tp_s[2048];
    __shared__ __align__(16) float tbar_s[256];

    const int tid = threadIdx.x;
    const int j0a = blockIdx.x * 8;

    if (blockIdx.x == 0 && tid == 0) cnts[0] = 0u;          // K34 counter; 1 full
                                                            // boundary downstream
    {   // Wn2 col-slice [256 rows][8 cols] at j0a -> wn2_s[r*8 + c]
        const int lane = tid & 63, wv = tid >> 6;
        const int r = lane >> 1, c4 = (lane & 1) << 2;
        for (int i = wv; i < 8; i += 4)
            async_cp16(Wn2 + (i*32 + r)*256 + j0a + c4, wn2_s + i*256);
    }
    stage_contig(tpart_ws, tp_s, 2048, tid);
    __syncthreads();

    {   // tbar: verbatim (q ascending, then *1/64)
        float tb = 0.f;
        #pragma unroll
        for (int q = 0; q < 8; ++q) tb += tp_s[q*256 + tid];
        tbar_s[tid] = tb * (1.f/64.f);
    }
    __syncthreads();

    if (tid < 8) {   // agg outputs j0a..j0a+7: verbatim chunk order
        float acc = bn2[j0a + tid];
        for (int jc = 0; jc < 256; jc += 32) {
            float w[32];
            #pragma unroll
            for (int u = 0; u < 32; ++u) w[u] = wn2_s[(jc+u)*8 + tid];
            #pragma unroll
            for (int u = 0; u < 32; u += 4) {
                const float4 t4 = *(const float4*)&tbar_s[jc + u];
                acc += t4.x*w[u] + t4.y*w[u+1] + t4.z*w[u+2] + t4.w*w[u+3];
            }
        }
        agg_ws[j0a + tid] = acc;
    }
}

// ---- K34 (16 blocks = 4 heads x 4 d-slices): heads h1 + last-arriver out --
__global__ __launch_bounds__(256) void k34_h1out(
    const float* __restrict__ Wh1, const float* __restrict__ bh1,
    const float* __restrict__ Wh2, const float* __restrict__ bh2,
    const float* __restrict__ agg_ws, float* __restrict__ h1h_ws,
    unsigned int* __restrict__ cnts, float* __restrict__ out)
{
    __shared__ __align__(16) float whs[256*32];             // 32 KB slice
    __shared__ __align__(16) float agg_s[256];
    __shared__ int last_s;

    const int tid = threadIdx.x;
    const int k   = blockIdx.x >> 2;
    const int d0  = (blockIdx.x & 3) * 32;

    stage_slice32(Wh1 + k*32768, whs, 128, d0, 256, tid);
    agg_s[tid] = agg_ws[tid];
    __syncthreads();                                        // drains both

    if (tid < 32) {   // per-output cc-chain VERBATIM (cc ascending 0..255)
        const int dl = tid;
        float a = bh1[k*128 + d0 + dl];
        for (int cc = 0; cc < 256; cc += 16) {
            float wa[16];
            #pragma unroll
            for (int u = 0; u < 16; ++u) wa[u] = whs[(cc+u)*32 + dl];
            #pragma unroll
            for (int u = 0; u < 16; u += 4) {
                const float4 a4 = *(const float4*)&agg_s[cc + u];
                a += a4.x*wa[u] + a4.y*wa[u+1] + a4.z*wa[u+2] + a4.w*wa[u+3];
            }
        }
        h1h_ws[k*128 + d0 + dl] = fmaxf(a, 0.f);
    }
    __threadfence();                     // release h1h stores device-wide
    __syncthreads();                     // all threads' fences complete
    if (tid == 0) {
        const unsigned old = __hip_atomic_fetch_add(
            &cnts[0], 1u, __ATOMIC_ACQ_REL, __HIP_MEMORY_SCOPE_AGENT);
        last_s = (old == 15u) ? 1 : 0;   // last arriver, no spinning
    }
    __syncthreads();
    if (last_s && tid < 4) {             // verbatim strictly-sequential dots
        const int kk = tid;
        float a = bh2[kk];
        for (int d = 0; d < 128; ++d)
            a += h1h_ws[kk*128 + d] * Wh2[kk*128 + d];
        out[kk] = a;
    }
}

extern "C" void kernel_launch(void* const* d_in, const int* in_sizes, int n_in,
                              void* d_out, int out_size, void* d_ws, size_t ws_size,
                              hipStream_t stream) {
    const float* positions = (const float*)d_in[0];
    const float* grid      = (const float*)d_in[1];
    const float* W1  = (const float*)d_in[2];
    const float* b1  = (const float*)d_in[3];
    const float* W2  = (const float*)d_in[4];
    const float* b2  = (const float*)d_in[5];
    const float* W3  = (const float*)d_in[6];
    const float* b3  = (const float*)d_in[7];
    const float* Wn1 = (const float*)d_in[8];
    const float* bn1 = (const float*)d_in[9];
    const float* Wn2 = (const float*)d_in[10];
    const float* bn2 = (const float*)d_in[11];
    const float* Wh1 = (const float*)d_in[12];
    const float* bh1 = (const float*)d_in[13];
    const float* Wh2 = (const float*)d_in[14];
    const float* bh2 = (const float*)d_in[15];
    float* out = (float*)d_out;

    char* ws = (char*)d_ws;                 // fully rewritten every call
    float* gf_ws    = (float*)(ws + 0);          // 64*256 f = 64 KB
    float* tpart_ws = (float*)(ws + 65536);      // 8*256 f = 8 KB
    float* agg_ws   = (float*)(ws + 73728);      // 256 f = 1 KB
    float* h1h_ws   = (float*)(ws + 74752);      // 4*128 f = 2 KB
    unsigned int* cnts = (unsigned int*)(ws + 76800);

    hipLaunchKernelGGL(k1a_gf,    dim3(64),  dim3(256), 0, stream,
                       positions, grid, W1, b1, W2, b2, W3, b3, gf_ws);
    hipLaunchKernelGGL(k1b_tpart, dim3(128), dim3(256), 0, stream,
                       Wn1, bn1, gf_ws, tpart_ws);
    hipLaunchKernelGGL(k2_agg,    dim3(32),  dim3(256), 0, stream,
                       Wn2, bn2, tpart_ws, agg_ws, cnts);
    hipLaunchKernelGGL(k34_h1out, dim3(16),  dim3(256), 0, stream,
                       Wh1, bh1, Wh2, bh2, agg_ws, h1h_ws, cnts, out);
}